// Round 5
// baseline (90.016 us; speedup 1.0000x reference)
//
#include <hip/hip_runtime.h>
#include <hip/hip_bf16.h>

#define NROWS 8192
#define DIM   128
#define NT    64                  // NROWS / 128 tiles per dim
#define NBLK  (NT * (NT + 1) / 2) // 2080 triangle tiles (divisible by 8: 8*260)
#define TOTAL_OUT 33550336u       // NROWS*(NROWS-1)/2

typedef short bf16x8 __attribute__((ext_vector_type(8)));
typedef float f32x4  __attribute__((ext_vector_type(4)));
typedef unsigned short u16x8 __attribute__((ext_vector_type(8)));

// fp32 -> bf16 round-to-nearest-even
static __device__ inline unsigned short f32_to_bf16(float f) {
    unsigned int u = __float_as_uint(f);
    u += 0x7FFFu + ((u >> 16) & 1u);
    return (unsigned short)(u >> 16);
}

// Block = one 16-row group. bf16 convert + FRAGMENT-MAJOR layout:
//   Xr[((g*4 + kk)*64 + lane)*8] : row g*16+(lane&15), cols ((kk*4+(lane>>4))*8 ..+8)
// Each MFMA fragment load in pdist = one contiguous 1KB wave load. Also fp32 norms.
__global__ __launch_bounds__(256) void prep_kernel(const float* __restrict__ X,
                                                   unsigned short* __restrict__ Xr,
                                                   float* __restrict__ sq,
                                                   float* __restrict__ out) {
    __shared__ float sm[16][17];
    const int g = blockIdx.x;
    const int t = threadIdx.x;
    const int kk = t >> 6, lane = t & 63;
    const int lrow = lane & 15, kgrp = lane >> 4;

    const float* src = X + (size_t)(g * 16 + lrow) * DIM + (kk * 4 + kgrp) * 8;
    const float4 v0 = *reinterpret_cast<const float4*>(src);
    const float4 v1 = *reinterpret_cast<const float4*>(src + 4);

    u16x8 h;
    h[0] = f32_to_bf16(v0.x); h[1] = f32_to_bf16(v0.y);
    h[2] = f32_to_bf16(v0.z); h[3] = f32_to_bf16(v0.w);
    h[4] = f32_to_bf16(v1.x); h[5] = f32_to_bf16(v1.y);
    h[6] = f32_to_bf16(v1.z); h[7] = f32_to_bf16(v1.w);
    *reinterpret_cast<u16x8*>(Xr + ((size_t)(g * 4 + kk) * 64 + lane) * 8) = h;

    float p = v0.x * v0.x + v0.y * v0.y + v0.z * v0.z + v0.w * v0.w
            + v1.x * v1.x + v1.y * v1.y + v1.z * v1.z + v1.w * v1.w;
    sm[lrow][kk * 4 + kgrp] = p;
    __syncthreads();
    if (t < 16) {
        float s = 0.f;
        #pragma unroll
        for (int j = 0; j < 16; ++j) s += sm[t][j];
        sq[g * 16 + t] = s;
    }
    if (g == 0 && t == 0) out[TOTAL_OUT - 1] = 0.0f; // skipped pair (0,1) slot
}

// 128x128 triangle tile, 4 waves (2x2), no LDS, fragment-major L2 loads.
// DENSE=1: block-sequential 64KB output chunks (ablation probe; wrong positions,
//          fully overwritten by the DENSE=0 launch that follows).
// DENSE=0: correct triangle scatter out[u*(u-1)/2 - 1 + l].
// Both use a chunked XCD swizzle (2080 = 8 * 260, bijective).
template <int DENSE>
__global__ __launch_bounds__(256, 4) void pdist_kernel(const unsigned short* __restrict__ Xr,
                                                       const float* __restrict__ sq,
                                                       float* __restrict__ out) {
    const int t    = threadIdx.x;
    const int phys = blockIdx.x;
    const int bt   = (phys & 7) * (NBLK / 8) + (phys >> 3);  // XCD-chunked swizzle
    // decode triangle index: bt = bj*(bj+1)/2 + bi, bi <= bj
    int bj = (int)((sqrtf(8.0f * (float)bt + 1.0f) - 1.0f) * 0.5f);
    while ((bj + 1) * (bj + 2) / 2 <= bt) ++bj;
    while (bj * (bj + 1) / 2 > bt) --bj;
    const int bi = bt - bj * (bj + 1) / 2;

    const int wid  = t >> 6;
    const int lane = t & 63;
    const int wr   = wid >> 1;   // wave row (l dim), 0..1
    const int wc   = wid & 1;    // wave col (u dim), 0..1
    const int lrow = lane & 15;
    const int kgrp = lane >> 4;

    const bf16x8* __restrict__ F = reinterpret_cast<const bf16x8*>(Xr);
    const int gA = bi * 8 + wr * 4;
    const int gB = bj * 8 + wc * 4;

    f32x4 acc[4][4];
    const f32x4 fzero = {0.f, 0.f, 0.f, 0.f};
    #pragma unroll
    for (int m = 0; m < 4; ++m)
        #pragma unroll
        for (int n = 0; n < 4; ++n) acc[m][n] = fzero;

    bf16x8 a[2][4], b[2][4];
    #pragma unroll
    for (int m = 0; m < 4; ++m) {
        a[0][m] = F[((gA + m) * 4 + 0) * 64 + lane];
        b[0][m] = F[((gB + m) * 4 + 0) * 64 + lane];
    }
    #pragma unroll
    for (int kk = 0; kk < 4; ++kk) {
        const int cur = kk & 1, nxt = cur ^ 1;
        if (kk < 3) {
            #pragma unroll
            for (int m = 0; m < 4; ++m) {
                a[nxt][m] = F[((gA + m) * 4 + kk + 1) * 64 + lane];
                b[nxt][m] = F[((gB + m) * 4 + kk + 1) * 64 + lane];
            }
        }
        #pragma unroll
        for (int m = 0; m < 4; ++m)
            #pragma unroll
            for (int n = 0; n < 4; ++n)
                acc[m][n] = __builtin_amdgcn_mfma_f32_16x16x32_bf16(a[cur][m], b[cur][n], acc[m][n], 0, 0, 0);
    }

    const int l0 = bi * 128 + wr * 64;
    const int u0 = bj * 128 + wc * 64;
    const int rj = kgrp * 4;

    float squ[4];
    f32x4 sql[4];
    #pragma unroll
    for (int n = 0; n < 4; ++n) squ[n] = sq[u0 + n * 16 + lrow];
    #pragma unroll
    for (int m = 0; m < 4; ++m)
        sql[m] = *reinterpret_cast<const f32x4*>(sq + l0 + m * 16 + rj);

    if (DENSE) {
        // block-sequential 64KB chunk, perfectly coalesced 1KB wave stores
        const size_t base = ((size_t)(unsigned)(bt % 2047)) * 16384u + (size_t)wid * 4096u;
        #pragma unroll
        for (int m = 0; m < 4; ++m) {
            #pragma unroll
            for (int n = 0; n < 4; ++n) {
                f32x4 d;
                #pragma unroll
                for (int j = 0; j < 4; ++j) d[j] = sql[m][j] + squ[n] - 2.0f * acc[m][n][j];
                __builtin_memcpy(out + base + (m * 4 + n) * 256 + lane * 4, &d, 16);
            }
        }
    } else if (bi != bj) {
        #pragma unroll
        for (int m = 0; m < 4; ++m) {
            #pragma unroll
            for (int n = 0; n < 4; ++n) {
                const int u = u0 + n * 16 + lrow;
                const size_t base = ((size_t)u * (u - 1)) / 2 - 1 + (size_t)(l0 + m * 16 + rj);
                f32x4 d;
                #pragma unroll
                for (int j = 0; j < 4; ++j) d[j] = sql[m][j] + squ[n] - 2.0f * acc[m][n][j];
                __builtin_memcpy(out + base, &d, 16);
            }
        }
    } else {
        // diagonal tile: mask l < u && u >= 2
        #pragma unroll
        for (int m = 0; m < 4; ++m) {
            #pragma unroll
            for (int n = 0; n < 4; ++n) {
                const int u = u0 + n * 16 + lrow;
                #pragma unroll
                for (int j = 0; j < 4; ++j) {
                    const int l = l0 + m * 16 + rj + j;
                    if (l < u && u >= 2) {
                        out[((size_t)u * (u - 1)) / 2 - 1 + l] = sql[m][j] + squ[n] - 2.0f * acc[m][n][j];
                    }
                }
            }
        }
    }
}

extern "C" void kernel_launch(void* const* d_in, const int* in_sizes, int n_in,
                              void* d_out, int out_size, void* d_ws, size_t ws_size,
                              hipStream_t stream) {
    const float* X = (const float*)d_in[0];
    float* out = (float*)d_out;
    unsigned short* Xr = (unsigned short*)d_ws;                       // 2 MB bf16, fragment-major
    float* sq = (float*)((char*)d_ws + (size_t)NROWS * DIM * 2);      // 32 KB norms

    prep_kernel<<<NROWS / 16, 256, 0, stream>>>(X, Xr, sq, out);
    // Ablation probe: identical compute, dense block-sequential stores.
    // Every location it writes is overwritten by the correct kernel below.
    pdist_kernel<1><<<NBLK, 256, 0, stream>>>(Xr, sq, out);
    // Correct triangle-scatter kernel (validated output).
    pdist_kernel<0><<<NBLK, 256, 0, stream>>>(Xr, sq, out);
}

// Round 6
// 59.809 us; speedup vs baseline: 1.5051x; 1.5051x over previous
//
#include <hip/hip_runtime.h>
#include <hip/hip_bf16.h>

#define NROWS 8192
#define DIM   128
#define TOTAL_OUT 33550336u       // NROWS*(NROWS-1)/2
#define NBLK_P 1280               // 512*(g>=384:4) + 384*(3) + 256*(2) + 128*(1) parts

typedef short bf16x8 __attribute__((ext_vector_type(8)));
typedef float f32x4  __attribute__((ext_vector_type(4)));
typedef unsigned short u16x8 __attribute__((ext_vector_type(8)));

// fp32 -> bf16 round-to-nearest-even
static __device__ inline unsigned short f32_to_bf16(float f) {
    unsigned int u = __float_as_uint(f);
    u += 0x7FFFu + ((u >> 16) & 1u);
    return (unsigned short)(u >> 16);
}

// Block = one 16-row group. bf16 convert + FRAGMENT-MAJOR layout:
//   Xr[((g*4 + kk)*64 + lane)*8] : row g*16+(lane&15), cols ((kk*4+(lane>>4))*8 ..+8)
// Each MFMA fragment load in pdist = one contiguous 1KB wave load. Also fp32 norms.
__global__ __launch_bounds__(256) void prep_kernel(const float* __restrict__ X,
                                                   unsigned short* __restrict__ Xr,
                                                   float* __restrict__ sq,
                                                   float* __restrict__ out) {
    __shared__ float sm[16][17];
    const int g = blockIdx.x;
    const int t = threadIdx.x;
    const int kk = t >> 6, lane = t & 63;
    const int lrow = lane & 15, kgrp = lane >> 4;

    const float* src = X + (size_t)(g * 16 + lrow) * DIM + (kk * 4 + kgrp) * 8;
    const float4 v0 = *reinterpret_cast<const float4*>(src);
    const float4 v1 = *reinterpret_cast<const float4*>(src + 4);

    u16x8 h;
    h[0] = f32_to_bf16(v0.x); h[1] = f32_to_bf16(v0.y);
    h[2] = f32_to_bf16(v0.z); h[3] = f32_to_bf16(v0.w);
    h[4] = f32_to_bf16(v1.x); h[5] = f32_to_bf16(v1.y);
    h[6] = f32_to_bf16(v1.z); h[7] = f32_to_bf16(v1.w);
    *reinterpret_cast<u16x8*>(Xr + ((size_t)(g * 4 + kk) * 64 + lane) * 8) = h;

    float p = v0.x * v0.x + v0.y * v0.y + v0.z * v0.z + v0.w * v0.w
            + v1.x * v1.x + v1.y * v1.y + v1.z * v1.z + v1.w * v1.w;
    sm[lrow][kk * 4 + kgrp] = p;
    __syncthreads();
    if (t < 16) {
        float s = 0.f;
        #pragma unroll
        for (int j = 0; j < 16; ++j) s += sm[t][j];
        sq[g * 16 + t] = s;
    }
    if (g == 0 && t == 0) out[TOTAL_OUT - 1] = 0.0f; // skipped pair (0,1) slot
}

// Row-owner tiling: block = 16 consecutive u-rows (group g) x contiguous l-tile
// range [t0,t1). Output per row is a contiguous stream written in address order
// by ONE block -> full-line L2 writeback, no read-allocate, page-sequential.
// Heavy groups split into up to 4 parts; blocks dispatched heaviest-first (LPT).
__global__ __launch_bounds__(256, 2) void pdist_kernel(const unsigned short* __restrict__ Xr,
                                                       const float* __restrict__ sq,
                                                       float* __restrict__ out) {
    __shared__ float smC[16][132];   // padded: +132 stride -> 2-way-max on writes

    const int t   = threadIdx.x;
    const int bid = blockIdx.x;
    // blockIdx -> (group g, part, nparts), heaviest groups first
    int g, part, np;
    if (bid < 512)       { g = 511 - (bid >> 2);        part = bid & 3;  np = 4; }
    else if (bid < 896)  { int q = bid - 512;  g = 383 - q / 3;  part = q % 3;  np = 3; }
    else if (bid < 1152) { int q = bid - 896;  g = 255 - (q >> 1); part = q & 1; np = 2; }
    else                 { g = 127 - (bid - 1152);      part = 0;      np = 1; }

    const int ext = (16 * g + 14) / 128 + 1;       // l-tiles needed: l <= 16g+14
    const int t0  = (ext * part) / np;
    const int t1  = (ext * (part + 1)) / np;

    const int wid  = t >> 6;
    const int lane = t & 63;
    const int lrow = lane & 15;
    const int kgrp = lane >> 4;
    const bf16x8* __restrict__ F = reinterpret_cast<const bf16x8*>(Xr);

    // A panel: the block's 16 u-rows, K=128, held in registers for all iters
    bf16x8 a[4];
    #pragma unroll
    for (int kk = 0; kk < 4; ++kk) a[kk] = F[(g * 4 + kk) * 64 + lane];

    // readback mapping: thread -> (row rr, col base cc) of the 16x128 tile
    const int rr = t >> 4;
    const int cc = (t & 15) * 8;
    const int u_t = 16 * g + rr;
    const float squ_t = sq[u_t];
    const size_t base_u = (u_t >= 2) ? ((size_t)u_t * (size_t)(u_t - 1) / 2 - 1) : 0;

    bf16x8 bA[2][4], bB[2][4];     // double-buffered B fragments (static indexing)
    auto loadB = [&](bf16x8 (&buf)[2][4], int lt) {
        #pragma unroll
        for (int n = 0; n < 2; ++n)
            #pragma unroll
            for (int kk = 0; kk < 4; ++kk)
                buf[n][kk] = F[((8 * lt + 2 * wid + n) * 4 + kk) * 64 + lane];
    };

    if (t0 < t1) loadB(bA, t0);
    for (int lt = t0; lt < t1; ++lt) {
        f32x4 acc[2];
        acc[0] = (f32x4){0.f, 0.f, 0.f, 0.f};
        acc[1] = (f32x4){0.f, 0.f, 0.f, 0.f};
        if ((lt - t0) & 1) {
            if (lt + 1 < t1) loadB(bA, lt + 1);
            #pragma unroll
            for (int kk = 0; kk < 4; ++kk) {
                acc[0] = __builtin_amdgcn_mfma_f32_16x16x32_bf16(a[kk], bB[0][kk], acc[0], 0, 0, 0);
                acc[1] = __builtin_amdgcn_mfma_f32_16x16x32_bf16(a[kk], bB[1][kk], acc[1], 0, 0, 0);
            }
        } else {
            if (lt + 1 < t1) loadB(bB, lt + 1);
            #pragma unroll
            for (int kk = 0; kk < 4; ++kk) {
                acc[0] = __builtin_amdgcn_mfma_f32_16x16x32_bf16(a[kk], bA[0][kk], acc[0], 0, 0, 0);
                acc[1] = __builtin_amdgcn_mfma_f32_16x16x32_bf16(a[kk], bA[1][kk], acc[1], 0, 0, 0);
            }
        }
        // transpose through LDS: acc row (kgrp*4+j) = u_local, col = l_local
        #pragma unroll
        for (int n = 0; n < 2; ++n)
            #pragma unroll
            for (int j = 0; j < 4; ++j)
                smC[kgrp * 4 + j][wid * 32 + n * 16 + lrow] = acc[n][j];
        __syncthreads();
        // readback + store: thread writes 8 consecutive l of one u-row (32B)
        {
            const int l0 = lt * 128 + cc;
            if (u_t >= 2 && l0 < u_t) {
                const float* srow = &smC[rr][cc];
                const f32x4 v0 = *reinterpret_cast<const f32x4*>(srow);
                const f32x4 v1 = *reinterpret_cast<const f32x4*>(srow + 4);
                if (l0 + 7 < u_t) {
                    const f32x4 s0 = *reinterpret_cast<const f32x4*>(sq + l0);
                    const f32x4 s1 = *reinterpret_cast<const f32x4*>(sq + l0 + 4);
                    f32x4 d0, d1;
                    #pragma unroll
                    for (int i = 0; i < 4; ++i) {
                        d0[i] = squ_t + s0[i] - 2.0f * v0[i];
                        d1[i] = squ_t + s1[i] - 2.0f * v1[i];
                    }
                    __builtin_memcpy(out + base_u + l0, &d0, 16);
                    __builtin_memcpy(out + base_u + l0 + 4, &d1, 16);
                } else {
                    #pragma unroll
                    for (int i = 0; i < 8; ++i) {
                        const int l = l0 + i;
                        if (l < u_t) {
                            const float v = (i < 4) ? v0[i] : v1[i - 4];
                            out[base_u + l] = squ_t + sq[l] - 2.0f * v;
                        }
                    }
                }
            }
        }
        __syncthreads();
    }
}

extern "C" void kernel_launch(void* const* d_in, const int* in_sizes, int n_in,
                              void* d_out, int out_size, void* d_ws, size_t ws_size,
                              hipStream_t stream) {
    const float* X = (const float*)d_in[0];
    float* out = (float*)d_out;
    unsigned short* Xr = (unsigned short*)d_ws;                       // 2 MB bf16, fragment-major
    float* sq = (float*)((char*)d_ws + (size_t)NROWS * DIM * 2);      // 32 KB norms

    prep_kernel<<<NROWS / 16, 256, 0, stream>>>(X, Xr, sq, out);
    pdist_kernel<<<NBLK_P, 256, 0, stream>>>(Xr, sq, out);
}